// Round 2
// baseline (444.474 us; speedup 1.0000x reference)
//
#include <hip/hip_runtime.h>
#include <hip/hip_bf16.h>

#define ALPHA_ 1.0f
#define BETA_  0.5f
#define GAMMA_ 0.3f
#define EPS_   1e-8f

typedef unsigned short u16;
typedef unsigned int u32;

constexpr int B_ = 32, C_ = 256, F_ = 2048;
constexpr int NTOT = B_ * C_ * F_;          // 16777216
constexpr int G8   = NTOT / 8;              // 2097152 (8 elems / thread-iter)
constexpr int NCC  = B_ * C_ * C_;          // 2097152

typedef __bf16 bf16x8 __attribute__((ext_vector_type(8)));
typedef float  f32x4  __attribute__((ext_vector_type(4)));

// round-to-nearest-even float -> bf16 bits (sin/cos inputs, no NaN/Inf)
__device__ __forceinline__ u16 f2bf(float x) {
    unsigned u = __float_as_uint(x);
    u += 0x7fffu + ((u >> 16) & 1u);
    return (u16)(u >> 16);
}

// ---------------------------------------------------------------------------
// Kernel A: elementwise mag/phase losses + combined-W bf16 (c,s interleaved
// per 8-element chunk: W byte layout row-major, row = b*256+r (8192 B/row),
// chunk q -> bytes [q*32, q*32+16) = cos, [q*32+16, q*32+32) = sin).
// Thread-work unit g covers 8 consecutive k of one row -> W bytes [32g,32g+32).
// ---------------------------------------------------------------------------
__global__ void __launch_bounds__(256)
ew_kernel(const float4* __restrict__ mh, const float4* __restrict__ ph,
          const float4* __restrict__ mt, const float4* __restrict__ pt,
          int4* __restrict__ W, float* __restrict__ accum)
{
    __shared__ float sm[4], sp[4];
    int tid    = blockIdx.x * 256 + threadIdx.x;
    int stride = gridDim.x * 256;           // 524288 -> 4 iters
    float msum = 0.f, psum = 0.f;

    #pragma unroll 2
    for (int g = tid; g < G8; g += stride) {
        float4 p0 = ph[2 * g], p1 = ph[2 * g + 1];
        float4 q0 = pt[2 * g], q1 = pt[2 * g + 1];
        float4 a0 = mh[2 * g], a1 = mh[2 * g + 1];
        float4 b0 = mt[2 * g], b1 = mt[2 * g + 1];

        float pv[8] = {p0.x, p0.y, p0.z, p0.w, p1.x, p1.y, p1.z, p1.w};
        float qv[8] = {q0.x, q0.y, q0.z, q0.w, q1.x, q1.y, q1.z, q1.w};
        float av[8] = {a0.x, a0.y, a0.z, a0.w, a1.x, a1.y, a1.z, a1.w};
        float bv[8] = {b0.x, b0.y, b0.z, b0.w, b1.x, b1.y, b1.z, b1.w};

        u32 cu[8], su[8];
        #pragma unroll
        for (int j = 0; j < 8; j++) {
            float dm = av[j] - bv[j];
            msum += dm * dm;
            psum += 1.f - __cosf(pv[j] - qv[j]);
            float s, c;
            __sincosf(pv[j], &s, &c);
            cu[j] = f2bf(c);
            su[j] = f2bf(s);
        }
        int4 cv = make_int4((int)(cu[0] | (cu[1] << 16)), (int)(cu[2] | (cu[3] << 16)),
                            (int)(cu[4] | (cu[5] << 16)), (int)(cu[6] | (cu[7] << 16)));
        int4 sv = make_int4((int)(su[0] | (su[1] << 16)), (int)(su[2] | (su[3] << 16)),
                            (int)(su[4] | (su[5] << 16)), (int)(su[6] | (su[7] << 16)));
        int4* dst = W + (size_t)g * 2;      // byte offset g*32
        dst[0] = cv;
        dst[1] = sv;
    }

    #pragma unroll
    for (int o = 32; o > 0; o >>= 1) {
        msum += __shfl_down(msum, o, 64);
        psum += __shfl_down(psum, o, 64);
    }
    int lane = threadIdx.x & 63, wv = threadIdx.x >> 6;
    if (lane == 0) { sm[wv] = msum; sp[wv] = psum; }
    __syncthreads();
    if (threadIdx.x == 0) {
        atomicAdd(&accum[0], sm[0] + sm[1] + sm[2] + sm[3]);
        atomicAdd(&accum[1], sp[0] + sp[1] + sp[2] + sp[3]);
    }
}

// ---------------------------------------------------------------------------
// Kernel B: batched MFMA -> pci -> (pci-target)^2 reduce.
// 64x64 tile/block, 4 waves of 32x32. BK=64 orig-k (256 B/row stage).
// Register double-buffer prefetch; LDS row stride 272 B (conflict-free).
// XCD swizzle: block g -> XCD g&7 hosts all 16 tiles of batches 4x..4x+3.
// ---------------------------------------------------------------------------
#define LSTR 272   // 256 data + 16 pad bytes per row (17 x int4)

__global__ void __launch_bounds__(256, 2)
pci_kernel(const u16* __restrict__ Wg, const float* __restrict__ tgt,
           float* __restrict__ accum)
{
    __shared__ int4 la4[64 * 17];
    __shared__ int4 lb4[64 * 17];
    __shared__ float sred[4];
    char* la = (char*)la4;
    char* lb = (char*)lb4;

    // swizzle
    const int g  = blockIdx.x;
    const int x  = g & 7, sq = g >> 3;
    const int y  = (x << 2) | (sq & 3);      // batch
    const int tt = sq >> 2;                  // tile 0..15
    const int ti = tt >> 2, tj = tt & 3;
    const int i0 = ti * 64, j0 = tj * 64;

    const int t    = threadIdx.x;
    const int lane = t & 63, wv = t >> 6;
    const int wrow = (wv >> 1) * 32, wcol = (wv & 1) * 32;
    const int m = lane & 15, q = lane >> 4;

    // staging: thread covers row (t>>4)+16r, 16 B at col (t&15)*16
    const int srow = t >> 4;
    const int scol = (t & 15) * 16;
    const char* Ab = (const char*)Wg + ((size_t)y * 256 + i0) * 8192;
    const char* Bb = (const char*)Wg + ((size_t)y * 256 + j0) * 8192;

    int4 pa[4], pb[4];
    #pragma unroll
    for (int r = 0; r < 4; r++) {
        pa[r] = *(const int4*)(Ab + (size_t)(srow + r * 16) * 8192 + scol);
        pb[r] = *(const int4*)(Bb + (size_t)(srow + r * 16) * 8192 + scol);
    }

    f32x4 zero = {0.f, 0.f, 0.f, 0.f};
    f32x4 accR[2][2], accSC[2][2], accCS[2][2];
    #pragma unroll
    for (int a = 0; a < 2; a++)
        #pragma unroll
        for (int c = 0; c < 2; c++) {
            accR[a][c] = zero; accSC[a][c] = zero; accCS[a][c] = zero;
        }

    for (int it = 0; it < 32; ++it) {
        __syncthreads();
        #pragma unroll
        for (int r = 0; r < 4; r++) {
            *(int4*)(la + (srow + r * 16) * LSTR + scol) = pa[r];
            *(int4*)(lb + (srow + r * 16) * LSTR + scol) = pb[r];
        }
        __syncthreads();

        if (it < 31) {
            const int koff = (it + 1) * 256;
            #pragma unroll
            for (int r = 0; r < 4; r++) {
                pa[r] = *(const int4*)(Ab + (size_t)(srow + r * 16) * 8192 + koff + scol);
                pb[r] = *(const int4*)(Bb + (size_t)(srow + r * 16) * 8192 + koff + scol);
            }
        }

        #pragma unroll
        for (int s = 0; s < 2; ++s) {
            bf16x8 fac[2], fas[2], fbc[2], fbs[2];
            #pragma unroll
            for (int a = 0; a < 2; a++) {
                const char* p = la + (wrow + a * 16 + m) * LSTR + s * 128 + q * 32;
                fac[a] = *(const bf16x8*)p;
                fas[a] = *(const bf16x8*)(p + 16);
            }
            #pragma unroll
            for (int c = 0; c < 2; c++) {
                const char* p = lb + (wcol + c * 16 + m) * LSTR + s * 128 + q * 32;
                fbc[c] = *(const bf16x8*)p;
                fbs[c] = *(const bf16x8*)(p + 16);
            }
            #pragma unroll
            for (int a = 0; a < 2; a++)
                #pragma unroll
                for (int c = 0; c < 2; c++) {
                    accR[a][c]  = __builtin_amdgcn_mfma_f32_16x16x32_bf16(fac[a], fbc[c], accR[a][c], 0, 0, 0);
                    accR[a][c]  = __builtin_amdgcn_mfma_f32_16x16x32_bf16(fas[a], fbs[c], accR[a][c], 0, 0, 0);
                    accSC[a][c] = __builtin_amdgcn_mfma_f32_16x16x32_bf16(fas[a], fbc[c], accSC[a][c], 0, 0, 0);
                    accCS[a][c] = __builtin_amdgcn_mfma_f32_16x16x32_bf16(fac[a], fbs[c], accCS[a][c], 0, 0, 0);
                }
        }
    }

    // epilogue: pci -> squared error vs target, accumulate
    const float inv_f = 1.0f / (float)F_;
    float coh = 0.f;
    const float* tb = tgt + (size_t)y * (C_ * C_);
    #pragma unroll
    for (int a = 0; a < 2; a++)
        #pragma unroll
        for (int c = 0; c < 2; c++) {
            int irow = i0 + wrow + a * 16 + q * 4;   // C/D: row=(lane>>4)*4+reg
            int jcol = j0 + wcol + c * 16 + m;       // C/D: col=lane&15
            #pragma unroll
            for (int r = 0; r < 4; r++) {
                float re = accR[a][c][r] * inv_f;
                float im = (accSC[a][c][r] - accCS[a][c][r]) * inv_f;
                float p  = sqrtf(re * re + im * im + EPS_);
                float d  = p - tb[(irow + r) * C_ + jcol];
                coh += d * d;
            }
        }

    #pragma unroll
    for (int o = 32; o > 0; o >>= 1) coh += __shfl_down(coh, o, 64);
    if (lane == 0) sred[wv] = coh;
    __syncthreads();
    if (t == 0) atomicAdd(&accum[2], sred[0] + sred[1] + sred[2] + sred[3]);
}

// ---------------------------------------------------------------------------
// Kernel C: finalize the 4 scalars
// ---------------------------------------------------------------------------
__global__ void fin_kernel(const float* __restrict__ accum, float* __restrict__ out)
{
    if (threadIdx.x == 0) {
        float mag = accum[0] * (1.0f / (float)NTOT);
        float phs = accum[1] * (1.0f / (float)NTOT);
        float coh = accum[2] * (1.0f / (float)NCC);
        out[0] = ALPHA_ * mag + BETA_ * phs + GAMMA_ * coh;
        out[1] = mag;
        out[2] = phs;
        out[3] = coh;
    }
}

extern "C" void kernel_launch(void* const* d_in, const int* in_sizes, int n_in,
                              void* d_out, int out_size, void* d_ws, size_t ws_size,
                              hipStream_t stream)
{
    const float* mh  = (const float*)d_in[0];
    const float* ph  = (const float*)d_in[1];
    const float* mt  = (const float*)d_in[2];
    const float* pt  = (const float*)d_in[3];
    const float* tgt = (const float*)d_in[4];
    float* out = (float*)d_out;

    // ws layout: [0..3] float accumulators | W (NTOT*2 bf16 = 64 MB)
    float* accum = (float*)d_ws;
    int4* W = (int4*)((char*)d_ws + 256);

    hipMemsetAsync(d_ws, 0, 16, stream);

    ew_kernel<<<2048, 256, 0, stream>>>(
        (const float4*)mh, (const float4*)ph, (const float4*)mt, (const float4*)pt,
        W, accum);

    pci_kernel<<<512, 256, 0, stream>>>((const u16*)W, tgt, accum);

    fin_kernel<<<1, 64, 0, stream>>>(accum, out);
}

// Round 3
// 309.816 us; speedup vs baseline: 1.4346x; 1.4346x over previous
//
#include <hip/hip_runtime.h>
#include <hip/hip_bf16.h>

#define ALPHA_ 1.0f
#define BETA_  0.5f
#define GAMMA_ 0.3f
#define EPS_   1e-8f

typedef unsigned short u16;
typedef unsigned int u32;

constexpr int B_ = 32, C_ = 256, F_ = 2048;
constexpr int NTOT = B_ * C_ * F_;          // 16777216
constexpr int G8   = NTOT / 8;              // 2097152 groups of 8 elems
constexpr int NCC  = B_ * C_ * C_;          // 2097152

typedef __bf16 bf16x8 __attribute__((ext_vector_type(8)));
typedef float  f32x4  __attribute__((ext_vector_type(4)));

// round-to-nearest-even float -> bf16 bits (sin/cos inputs, no NaN/Inf)
__device__ __forceinline__ u32 f2bf(float x) {
    unsigned u = __float_as_uint(x);
    u += 0x7fffu + ((u >> 16) & 1u);
    return (u >> 16);
}

// async global->LDS, 16 B per lane; LDS dst = wave-uniform base + lane*16
__device__ __forceinline__ void async_copy16(const void* g, void* l) {
    __builtin_amdgcn_global_load_lds(
        (const __attribute__((address_space(1))) unsigned int*)g,
        (__attribute__((address_space(3))) unsigned int*)l,
        16, 0, 0);
}

// ---------------------------------------------------------------------------
// Kernel A: elementwise mag/phase losses + cos/sin(phase_hat) as bf16 in ws.
// 8 elems/thread/group, 2 groups' loads (16x float4) in flight per iter.
// ---------------------------------------------------------------------------
__device__ __forceinline__ void ew_body(int g,
    float4 p0, float4 p1, float4 q0, float4 q1,
    float4 a0, float4 a1, float4 b0, float4 b1,
    float& msum, float& psum, int4* __restrict__ cb4, int4* __restrict__ sb4)
{
    float pv[8] = {p0.x, p0.y, p0.z, p0.w, p1.x, p1.y, p1.z, p1.w};
    float qv[8] = {q0.x, q0.y, q0.z, q0.w, q1.x, q1.y, q1.z, q1.w};
    float av[8] = {a0.x, a0.y, a0.z, a0.w, a1.x, a1.y, a1.z, a1.w};
    float bv[8] = {b0.x, b0.y, b0.z, b0.w, b1.x, b1.y, b1.z, b1.w};
    u32 cu[8], su[8];
    #pragma unroll
    for (int j = 0; j < 8; j++) {
        float dm = av[j] - bv[j];
        msum += dm * dm;
        psum += 1.f - __cosf(pv[j] - qv[j]);
        float s, c;
        __sincosf(pv[j], &s, &c);
        cu[j] = f2bf(c);
        su[j] = f2bf(s);
    }
    cb4[g] = make_int4((int)(cu[0] | (cu[1] << 16)), (int)(cu[2] | (cu[3] << 16)),
                       (int)(cu[4] | (cu[5] << 16)), (int)(cu[6] | (cu[7] << 16)));
    sb4[g] = make_int4((int)(su[0] | (su[1] << 16)), (int)(su[2] | (su[3] << 16)),
                       (int)(su[4] | (su[5] << 16)), (int)(su[6] | (su[7] << 16)));
}

__global__ void __launch_bounds__(256)
ew_kernel(const float4* __restrict__ mh, const float4* __restrict__ ph,
          const float4* __restrict__ mt, const float4* __restrict__ pt,
          int4* __restrict__ cb4, int4* __restrict__ sb4,
          float* __restrict__ accum)
{
    __shared__ float sm[4], sp[4];
    const int tid    = blockIdx.x * 256 + threadIdx.x;
    const int stride = 2048 * 256;          // 524288; G8/stride = 4
    float msum = 0.f, psum = 0.f;

    #pragma unroll
    for (int half = 0; half < 2; ++half) {
        int g0 = tid + (2 * half) * stride;
        int g1 = g0 + stride;
        // issue all 16 loads before any compute
        float4 p00 = ph[2*g0], p01 = ph[2*g0+1];
        float4 q00 = pt[2*g0], q01 = pt[2*g0+1];
        float4 a00 = mh[2*g0], a01 = mh[2*g0+1];
        float4 b00 = mt[2*g0], b01 = mt[2*g0+1];
        float4 p10 = ph[2*g1], p11 = ph[2*g1+1];
        float4 q10 = pt[2*g1], q11 = pt[2*g1+1];
        float4 a10 = mh[2*g1], a11 = mh[2*g1+1];
        float4 b10 = mt[2*g1], b11 = mt[2*g1+1];
        ew_body(g0, p00, p01, q00, q01, a00, a01, b00, b01, msum, psum, cb4, sb4);
        ew_body(g1, p10, p11, q10, q11, a10, a11, b10, b11, msum, psum, cb4, sb4);
    }

    #pragma unroll
    for (int o = 32; o > 0; o >>= 1) {
        msum += __shfl_down(msum, o, 64);
        psum += __shfl_down(psum, o, 64);
    }
    int lane = threadIdx.x & 63, wv = threadIdx.x >> 6;
    if (lane == 0) { sm[wv] = msum; sp[wv] = psum; }
    __syncthreads();
    if (threadIdx.x == 0) {
        atomicAdd(&accum[0], sm[0] + sm[1] + sm[2] + sm[3]);
        atomicAdd(&accum[1], sp[0] + sp[1] + sp[2] + sp[3]);
    }
}

// ---------------------------------------------------------------------------
// Kernel B: batched MFMA -> pci -> (pci-target)^2 reduce.
// 64x64 tile/block, 4 waves of 32x32, BK=64.
// Staging via global_load_lds (16B) -> zero staging VGPRs, no LDS stores.
// LDS row = 256 B = 16 chunks of 16 B; chunk c of row r stored at physical
// chunk c ^ (r&15) (XOR swizzle folded into the per-lane GLOBAL address,
// since direct-to-LDS destination is fixed at base + lane*16).
// Logical chunks: c=0..7 -> cos k-slab, c=8..15 -> sin k-slab.
// ---------------------------------------------------------------------------
__global__ void __launch_bounds__(256)
pci_kernel(const u16* __restrict__ cb, const u16* __restrict__ sb,
           const float* __restrict__ tgt, float* __restrict__ accum)
{
    __shared__ char lds[32768];          // A tile 16 KB | B tile 16 KB
    __shared__ float sred[4];
    char* la = lds;
    char* lb = lds + 16384;

    // XCD swizzle: blocks g with g&7 == x form batches 4x..4x+3 on one XCD
    const int g  = blockIdx.x;
    const int x  = g & 7, sq = g >> 3;
    const int y  = (x << 2) | (sq & 3);      // batch
    const int tt = sq >> 2;                  // tile 0..15
    const int i0 = (tt >> 2) * 64, j0 = (tt & 3) * 64;

    const int t    = threadIdx.x;
    const int lane = t & 63, w = t >> 6;
    const int wrow = (w >> 1) * 32, wcol = (w & 1) * 32;
    const int m = lane & 15, q = lane >> 4;

    // staging source pointers: wave w, instr r covers rows w*16+r*4 .. +4,
    // lane covers row += lane>>4, physical chunk p = lane&15.
    const char* gA[4];
    const char* gB[4];
    {
        const int p = lane & 15;
        #pragma unroll
        for (int r = 0; r < 4; ++r) {
            int row = w * 16 + r * 4 + (lane >> 4);
            int c   = p ^ (row & 15);            // logical chunk
            const u16* arr = (c < 8) ? cb : sb;  // cos | sin stream
            int cc = c & 7;                      // 16B chunk within 128B slab
            gA[r] = (const char*)arr + ((size_t)(y * 256 + i0 + row)) * 4096 + cc * 16;
            gB[r] = (const char*)arr + ((size_t)(y * 256 + j0 + row)) * 4096 + cc * 16;
        }
    }

    f32x4 zero = {0.f, 0.f, 0.f, 0.f};
    f32x4 accR[2][2], accSC[2][2], accCS[2][2];
    #pragma unroll
    for (int a = 0; a < 2; a++)
        #pragma unroll
        for (int c = 0; c < 2; c++) {
            accR[a][c] = zero; accSC[a][c] = zero; accCS[a][c] = zero;
        }

    for (int it = 0; it < 32; ++it) {
        __syncthreads();                    // protect LDS from prior reads
        #pragma unroll
        for (int r = 0; r < 4; ++r) {
            async_copy16(gA[r], la + w * 4096 + r * 1024);
            async_copy16(gB[r], lb + w * 4096 + r * 1024);
            gA[r] += 128; gB[r] += 128;     // 64 k per iter = 128 B per stream
        }
        __syncthreads();                    // drains vmcnt(0) + barrier

        #pragma unroll
        for (int s = 0; s < 2; ++s) {
            bf16x8 fac[2], fas[2], fbc[2], fbs[2];
            #pragma unroll
            for (int a = 0; a < 2; a++) {
                const char* base = la + (wrow + a * 16 + m) * 256;
                int pc = ((4 * s + q) ^ m) * 16;     // cos physical chunk
                fac[a] = *(const bf16x8*)(base + pc);
                fas[a] = *(const bf16x8*)(base + (pc ^ 128)); // sin = cos ^ bit3
            }
            #pragma unroll
            for (int c = 0; c < 2; c++) {
                const char* base = lb + (wcol + c * 16 + m) * 256;
                int pc = ((4 * s + q) ^ m) * 16;
                fbc[c] = *(const bf16x8*)(base + pc);
                fbs[c] = *(const bf16x8*)(base + (pc ^ 128));
            }
            #pragma unroll
            for (int a = 0; a < 2; a++)
                #pragma unroll
                for (int c = 0; c < 2; c++) {
                    accR[a][c]  = __builtin_amdgcn_mfma_f32_16x16x32_bf16(fac[a], fbc[c], accR[a][c], 0, 0, 0);
                    accR[a][c]  = __builtin_amdgcn_mfma_f32_16x16x32_bf16(fas[a], fbs[c], accR[a][c], 0, 0, 0);
                    accSC[a][c] = __builtin_amdgcn_mfma_f32_16x16x32_bf16(fas[a], fbc[c], accSC[a][c], 0, 0, 0);
                    accCS[a][c] = __builtin_amdgcn_mfma_f32_16x16x32_bf16(fac[a], fbs[c], accCS[a][c], 0, 0, 0);
                }
        }
    }

    // epilogue: pci -> squared error vs target, accumulate
    const float inv_f = 1.0f / (float)F_;
    float coh = 0.f;
    const float* tb = tgt + (size_t)y * (C_ * C_);
    #pragma unroll
    for (int a = 0; a < 2; a++)
        #pragma unroll
        for (int c = 0; c < 2; c++) {
            int irow = i0 + wrow + a * 16 + q * 4;   // C/D: row=(lane>>4)*4+reg
            int jcol = j0 + wcol + c * 16 + m;       // C/D: col=lane&15
            #pragma unroll
            for (int r = 0; r < 4; r++) {
                float re = accR[a][c][r] * inv_f;
                float im = (accSC[a][c][r] - accCS[a][c][r]) * inv_f;
                float p  = sqrtf(re * re + im * im + EPS_);
                float d  = p - tb[(irow + r) * C_ + jcol];
                coh += d * d;
            }
        }

    #pragma unroll
    for (int o = 32; o > 0; o >>= 1) coh += __shfl_down(coh, o, 64);
    if (lane == 0) sred[w] = coh;
    __syncthreads();
    if (t == 0) atomicAdd(&accum[2], sred[0] + sred[1] + sred[2] + sred[3]);
}

// ---------------------------------------------------------------------------
// Kernel C: finalize the 4 scalars
// ---------------------------------------------------------------------------
__global__ void fin_kernel(const float* __restrict__ accum, float* __restrict__ out)
{
    if (threadIdx.x == 0) {
        float mag = accum[0] * (1.0f / (float)NTOT);
        float phs = accum[1] * (1.0f / (float)NTOT);
        float coh = accum[2] * (1.0f / (float)NCC);
        out[0] = ALPHA_ * mag + BETA_ * phs + GAMMA_ * coh;
        out[1] = mag;
        out[2] = phs;
        out[3] = coh;
    }
}

extern "C" void kernel_launch(void* const* d_in, const int* in_sizes, int n_in,
                              void* d_out, int out_size, void* d_ws, size_t ws_size,
                              hipStream_t stream)
{
    const float* mh  = (const float*)d_in[0];
    const float* ph  = (const float*)d_in[1];
    const float* mt  = (const float*)d_in[2];
    const float* pt  = (const float*)d_in[3];
    const float* tgt = (const float*)d_in[4];
    float* out = (float*)d_out;

    // ws layout: [0..3] float accumulators | cb (32 MB) | sb (32 MB)
    float* accum = (float*)d_ws;
    u16* cb = (u16*)((char*)d_ws + 256);
    u16* sb = cb + (size_t)NTOT;

    hipMemsetAsync(d_ws, 0, 16, stream);

    ew_kernel<<<2048, 256, 0, stream>>>(
        (const float4*)mh, (const float4*)ph, (const float4*)mt, (const float4*)pt,
        (int4*)cb, (int4*)sb, accum);

    pci_kernel<<<512, 256, 0, stream>>>(cb, sb, tgt, accum);

    fin_kernel<<<1, 64, 0, stream>>>(accum, out);
}